// Round 1
// baseline (329.647 us; speedup 1.0000x reference)
//
#include <hip/hip_runtime.h>
#include <hip/hip_bf16.h>

#define NRES 256
#define DPAIR 128
#define NHEADS 16
#define DHEAD 32
#define DINNER 512

typedef unsigned short u16;
typedef __attribute__((ext_vector_type(4))) float f32x4;
typedef __attribute__((ext_vector_type(8))) short s16x8;

__device__ __forceinline__ u16 f32_to_bf16(float f) {
    unsigned int u = __builtin_bit_cast(unsigned int, f);
    unsigned int r = (u + 0x7FFFu + ((u >> 16) & 1u)) >> 16;
    return (u16)r;
}

// ---------------- Kernel 0: weight convert + transpose to bf16 ----------------
// Wq/Wk/Wv (128x512 f32) -> Wt[n(512)][k(128)] bf16 ; Wo (512x128) -> WoT[n(128)][k(512)]
__global__ __launch_bounds__(256) void wconv(const float* __restrict__ Wq,
                                             const float* __restrict__ Wk,
                                             const float* __restrict__ Wv,
                                             const float* __restrict__ Wo,
                                             u16* wq_t, u16* wk_t, u16* wv_t, u16* wo_t) {
    int id = blockIdx.x * 256 + threadIdx.x;
    if (id < 3 * 65536) {
        int m = id / 65536;
        int e = id % 65536;
        int k = e >> 9, n = e & 511;            // W row-major [k][n], coalesced read
        const float* W = (m == 0) ? Wq : ((m == 1) ? Wk : Wv);
        u16* Wt = (m == 0) ? wq_t : ((m == 1) ? wk_t : wv_t);
        Wt[n * 128 + k] = f32_to_bf16(W[e]);
    } else {
        int e = id - 3 * 65536;                 // Wo [k(512)][n(128)]
        int k = e >> 7, n = e & 127;
        wo_t[n * 512 + k] = f32_to_bf16(Wo[e]);
    }
}

// ---------------- Kernel 1: QKV projection GEMM ----------------
// grid 512 blocks: each does 128 rows x (3 x 512) cols, K=128.
// q,k stored [row(65536)][col(512)] bf16 ; v stored transposed vT[(i*512+col)][j] bf16
__global__ __launch_bounds__(256) void qkv_proj(const float* __restrict__ pair,
                                                const u16* __restrict__ wq_t,
                                                const u16* __restrict__ wk_t,
                                                const u16* __restrict__ wv_t,
                                                const float* __restrict__ bq,
                                                const float* __restrict__ bk,
                                                const float* __restrict__ bv,
                                                u16* __restrict__ q_ws,
                                                u16* __restrict__ k_ws,
                                                u16* __restrict__ vT_ws) {
    __shared__ u16 As[128 * 136];   // 128 rows x 128 k, pitch 136 (bank-safe)
    __shared__ u16 Bs[64 * 136];    // 64 n x 128 k
    const int tid = threadIdx.x;
    const int m0 = blockIdx.x * 128;

    // stage A (pair rows, fp32 -> bf16)
    for (int it = 0; it < 16; ++it) {
        int L = tid + it * 256;
        int row = L >> 5, c4 = L & 31;
        const float4 v = *(reinterpret_cast<const float4*>(pair + (size_t)(m0 + row) * 128) + c4);
        u16 b0 = f32_to_bf16(v.x), b1 = f32_to_bf16(v.y), b2 = f32_to_bf16(v.z), b3 = f32_to_bf16(v.w);
        ushort4 pk; pk.x = b0; pk.y = b1; pk.z = b2; pk.w = b3;
        *reinterpret_cast<ushort4*>(&As[row * 136 + c4 * 4]) = pk;
    }

    const int wave = tid >> 6, lane = tid & 63;
    const int g = lane >> 4, l15 = lane & 15;

    for (int nt = 0; nt < 24; ++nt) {
        const int mat = nt >> 3;
        const int ncol0 = (nt & 7) * 64;
        const u16* Wt = (mat == 0) ? wq_t : ((mat == 1) ? wk_t : wv_t);
        const float* bias = (mat == 0) ? bq : ((mat == 1) ? bk : bv);

        __syncthreads();
        // stage B tile: 64 n-rows x 128 k contiguous
        for (int it = 0; it < 4; ++it) {
            int L = tid + it * 256;
            int n = L >> 4, seg = L & 15;
            *reinterpret_cast<s16x8*>(&Bs[n * 136 + seg * 8]) =
                *reinterpret_cast<const s16x8*>(Wt + (size_t)(ncol0 + n) * 128 + seg * 8);
        }
        __syncthreads();

        f32x4 acc[2][4];
        for (int r = 0; r < 2; ++r) for (int c = 0; c < 4; ++c) acc[r][c] = f32x4{0.f, 0.f, 0.f, 0.f};

        for (int kk = 0; kk < 4; ++kk) {
            s16x8 a[2], b[4];
            a[0] = *reinterpret_cast<s16x8*>(&As[(wave * 32 + l15) * 136 + kk * 32 + g * 8]);
            a[1] = *reinterpret_cast<s16x8*>(&As[(wave * 32 + 16 + l15) * 136 + kk * 32 + g * 8]);
            for (int c = 0; c < 4; ++c)
                b[c] = *reinterpret_cast<s16x8*>(&Bs[(c * 16 + l15) * 136 + kk * 32 + g * 8]);
            for (int r = 0; r < 2; ++r)
                for (int c = 0; c < 4; ++c)
                    acc[r][c] = __builtin_amdgcn_mfma_f32_16x16x32_bf16(a[r], b[c], acc[r][c], 0, 0, 0);
        }

        // epilogue
        for (int r = 0; r < 2; ++r) {
            for (int c = 0; c < 4; ++c) {
                const int col = ncol0 + c * 16 + l15;   // 0..511 within this matrix
                const float bval = bias[col];
                const int rowb = m0 + wave * 32 + r * 16 + g * 4;
                if (mat < 2) {
                    u16* dst = (mat == 0) ? q_ws : k_ws;
                    for (int rr = 0; rr < 4; ++rr)
                        dst[(size_t)(rowb + rr) * 512 + col] = f32_to_bf16(acc[r][c][rr] + bval);
                } else {
                    // vT[(i*512 + col)*256 + j]; rows rowb..rowb+3 are consecutive j within one i
                    const int i_ = rowb >> 8, j_ = rowb & 255;
                    u16* dst = vT_ws + ((size_t)i_ * 512 + col) * 256 + j_;
                    for (int p = 0; p < 2; ++p) {
                        unsigned int pack = (unsigned)f32_to_bf16(acc[r][c][2 * p] + bval) |
                                            ((unsigned)f32_to_bf16(acc[r][c][2 * p + 1] + bval) << 16);
                        *reinterpret_cast<unsigned int*>(dst + 2 * p) = pack;
                    }
                }
            }
        }
    }
}

// ---------------- Kernel 2: triangular attention per (i,h) ----------------
// o aliases q in ws: each block reads exactly q[i,:,h*32..] into LDS (barrier), then
// writes o to the same region -- race-free across blocks (disjoint regions).
__global__ __launch_bounds__(256) void attn(const u16* __restrict__ k_ws,
                                            const u16* __restrict__ vT_ws,
                                            u16* qo_ws) {
    __shared__ u16 Qs[256 * 40];    // 256 rows x 32 c, pitch 40
    __shared__ u16 Ks[256 * 40];
    __shared__ u16 Vt[32 * 264];    // 32 c x 256 keys, pitch 264
    __shared__ u16 Ps[64 * 264];    // 4 waves x 16 rows x 256 keys

    const int bx = blockIdx.x;
    const int i = bx >> 4, h = bx & 15;
    const int tid = threadIdx.x;
    const size_t qbase = ((size_t)i * 256) * 512 + h * 32;

    for (int it = 0; it < 4; ++it) {
        int L = tid + it * 256;
        int row = L >> 2, seg = L & 3;
        *reinterpret_cast<s16x8*>(&Qs[row * 40 + seg * 8]) =
            *reinterpret_cast<const s16x8*>(qo_ws + qbase + (size_t)row * 512 + seg * 8);
        *reinterpret_cast<s16x8*>(&Ks[row * 40 + seg * 8]) =
            *reinterpret_cast<const s16x8*>(k_ws + qbase + (size_t)row * 512 + seg * 8);
    }
    const size_t vbase = ((size_t)i * 512 + h * 32) * 256;
    for (int it = 0; it < 4; ++it) {
        int L = tid + it * 256;
        int c = L >> 5, seg = L & 31;
        *reinterpret_cast<s16x8*>(&Vt[c * 264 + seg * 8]) =
            *reinterpret_cast<const s16x8*>(vT_ws + vbase + (size_t)c * 256 + seg * 8);
    }
    __syncthreads();

    const int wave = tid >> 6, lane = tid & 63;
    const int g = lane >> 4, l15 = lane & 15;
    const float scale = 0.17677669529663687f;  // 1/sqrt(32)

    for (int ch = 0; ch < 4; ++ch) {
        const int jbase = wave * 64 + ch * 16;

        // S = Q Kt : 16 fragments over key tiles (K-dim = 32 = one MFMA)
        f32x4 s[16];
        for (int kt = 0; kt < 16; ++kt) s[kt] = f32x4{0.f, 0.f, 0.f, 0.f};
        const s16x8 aq = *reinterpret_cast<s16x8*>(&Qs[(jbase + l15) * 40 + g * 8]);
        for (int kt = 0; kt < 16; ++kt) {
            const s16x8 bk_ = *reinterpret_cast<s16x8*>(&Ks[(kt * 16 + l15) * 40 + g * 8]);
            s[kt] = __builtin_amdgcn_mfma_f32_16x16x32_bf16(aq, bk_, s[kt], 0, 0, 0);
        }

        // mask + scale + row max
        float mx[4] = {-3.0e38f, -3.0e38f, -3.0e38f, -3.0e38f};
        for (int kt = 0; kt < 16; ++kt) {
            const int k0 = kt * 16 + l15;
            for (int r = 0; r < 4; ++r) {
                const int j = jbase + g * 4 + r;
                float v = s[kt][r] * scale;
                if (k0 > j) v = -1e30f;
                s[kt][r] = v;
                mx[r] = fmaxf(mx[r], v);
            }
        }
        for (int r = 0; r < 4; ++r)
            for (int off = 1; off < 16; off <<= 1)
                mx[r] = fmaxf(mx[r], __shfl_xor(mx[r], off, 64));

        float sum[4] = {0.f, 0.f, 0.f, 0.f};
        for (int kt = 0; kt < 16; ++kt)
            for (int r = 0; r < 4; ++r) {
                const float e = __expf(s[kt][r] - mx[r]);
                s[kt][r] = e;
                sum[r] += e;
            }
        for (int r = 0; r < 4; ++r)
            for (int off = 1; off < 16; off <<= 1)
                sum[r] += __shfl_xor(sum[r], off, 64);

        // P -> LDS (bf16, row-major pitch 264)
        for (int kt = 0; kt < 16; ++kt)
            for (int r = 0; r < 4; ++r)
                Ps[(wave * 16 + g * 4 + r) * 264 + kt * 16 + l15] = f32_to_bf16(s[kt][r]);

        // O = P V : 2 c-tiles x 8 K-steps
        f32x4 o[2];
        o[0] = f32x4{0.f, 0.f, 0.f, 0.f};
        o[1] = f32x4{0.f, 0.f, 0.f, 0.f};
        for (int kk = 0; kk < 8; ++kk) {
            const s16x8 pa = *reinterpret_cast<s16x8*>(&Ps[(wave * 16 + l15) * 264 + kk * 32 + g * 8]);
            for (int ct = 0; ct < 2; ++ct) {
                const s16x8 vb = *reinterpret_cast<s16x8*>(&Vt[(ct * 16 + l15) * 264 + kk * 32 + g * 8]);
                o[ct] = __builtin_amdgcn_mfma_f32_16x16x32_bf16(pa, vb, o[ct], 0, 0, 0);
            }
        }

        // normalize + store (same (row<->reg) mapping as softmax sums)
        for (int ct = 0; ct < 2; ++ct)
            for (int r = 0; r < 4; ++r) {
                const int j = jbase + g * 4 + r;
                const float val = o[ct][r] / sum[r];
                qo_ws[qbase + (size_t)j * 512 + ct * 16 + l15] = f32_to_bf16(val);
            }
    }
}

// ---------------- Kernel 3: output projection + residual ----------------
// out = pair + o @ Wo + bo ; o bf16 [65536][512], WoT [128][512]
__global__ __launch_bounds__(256) void outproj(const u16* __restrict__ o_ws,
                                               const u16* __restrict__ wo_t,
                                               const float* __restrict__ pair,
                                               const float* __restrict__ bo,
                                               float* __restrict__ out) {
    __shared__ u16 As[64 * 72];     // 64 rows x 64 k
    __shared__ u16 Bs[128 * 72];    // 128 n x 64 k
    const int tid = threadIdx.x;
    const int m0 = blockIdx.x * 64;
    const int wave = tid >> 6, lane = tid & 63;
    const int g = lane >> 4, l15 = lane & 15;

    f32x4 acc[8];
    for (int c = 0; c < 8; ++c) acc[c] = f32x4{0.f, 0.f, 0.f, 0.f};

    for (int kt = 0; kt < 8; ++kt) {
        __syncthreads();
        for (int it = 0; it < 2; ++it) {
            int L = tid + it * 256;
            int row = L >> 3, seg = L & 7;
            *reinterpret_cast<s16x8*>(&As[row * 72 + seg * 8]) =
                *reinterpret_cast<const s16x8*>(o_ws + (size_t)(m0 + row) * 512 + kt * 64 + seg * 8);
        }
        for (int it = 0; it < 4; ++it) {
            int L = tid + it * 256;
            int n = L >> 3, seg = L & 7;
            *reinterpret_cast<s16x8*>(&Bs[n * 72 + seg * 8]) =
                *reinterpret_cast<const s16x8*>(wo_t + (size_t)n * 512 + kt * 64 + seg * 8);
        }
        __syncthreads();
        for (int kk = 0; kk < 2; ++kk) {
            const s16x8 a = *reinterpret_cast<s16x8*>(&As[(wave * 16 + l15) * 72 + kk * 32 + g * 8]);
            for (int c = 0; c < 8; ++c) {
                const s16x8 b = *reinterpret_cast<s16x8*>(&Bs[(c * 16 + l15) * 72 + kk * 32 + g * 8]);
                acc[c] = __builtin_amdgcn_mfma_f32_16x16x32_bf16(a, b, acc[c], 0, 0, 0);
            }
        }
    }

    for (int c = 0; c < 8; ++c) {
        const int n = c * 16 + l15;
        const float bias = bo[n];
        for (int r = 0; r < 4; ++r) {
            const size_t row = m0 + wave * 16 + g * 4 + r;
            out[row * 128 + n] = acc[c][r] + bias + pair[row * 128 + n];
        }
    }
}

extern "C" void kernel_launch(void* const* d_in, const int* in_sizes, int n_in,
                              void* d_out, int out_size, void* d_ws, size_t ws_size,
                              hipStream_t stream) {
    const float* pair = (const float*)d_in[0];
    const float* Wq = (const float*)d_in[1];
    const float* bq = (const float*)d_in[2];
    const float* Wk = (const float*)d_in[3];
    const float* bk = (const float*)d_in[4];
    const float* Wv = (const float*)d_in[5];
    const float* bv = (const float*)d_in[6];
    const float* Wo = (const float*)d_in[7];
    const float* bo = (const float*)d_in[8];
    float* out = (float*)d_out;

    char* ws = (char*)d_ws;
    u16* q_ws  = (u16*)(ws);                       // 65536*512*2 = 64 MiB (aliased as o)
    u16* k_ws  = (u16*)(ws + 67108864);            // 64 MiB
    u16* vT_ws = (u16*)(ws + 134217728);           // 64 MiB
    u16* wq_t  = (u16*)(ws + 201326592);           // 512*128*2
    u16* wk_t  = wq_t + 65536;
    u16* wv_t  = wk_t + 65536;
    u16* wo_t  = wv_t + 65536;

    wconv<<<1024, 256, 0, stream>>>(Wq, Wk, Wv, Wo, wq_t, wk_t, wv_t, wo_t);
    qkv_proj<<<512, 256, 0, stream>>>(pair, wq_t, wk_t, wv_t, bq, bk, bv, q_ws, k_ws, vT_ws);
    attn<<<4096, 256, 0, stream>>>(k_ws, vT_ws, q_ws);
    outproj<<<1024, 256, 0, stream>>>(q_ws, wo_t, pair, bo, out);
}

// Round 2
// 155.749 us; speedup vs baseline: 2.1165x; 2.1165x over previous
//
#include <hip/hip_runtime.h>
#include <hip/hip_bf16.h>

#define NRES 256
#define DPAIR 128
#define NHEADS 16
#define DHEAD 32
#define DINNER 512

typedef unsigned short u16;
typedef __attribute__((ext_vector_type(4))) float f32x4;
typedef __attribute__((ext_vector_type(8))) short s16x8;
typedef __attribute__((ext_vector_type(4))) short s16x4;

// (1/sqrt(32)) * log2(e): folded into q so softmax can use exp2 directly.
#define QSCALE 0.17677669529663687f * 1.4426950408889634f

__device__ __forceinline__ u16 f32_to_bf16(float f) {
    unsigned int u = __builtin_bit_cast(unsigned int, f);
    unsigned int r = (u + 0x7FFFu + ((u >> 16) & 1u)) >> 16;
    return (u16)r;
}

__device__ __forceinline__ float fast_exp2(float x) {
#if __has_builtin(__builtin_amdgcn_exp2f)
    return __builtin_amdgcn_exp2f(x);
#else
    return exp2f(x);
#endif
}

__device__ __forceinline__ f32x4 mfma_16x16x16_bf16(s16x4 a, s16x4 b, f32x4 c) {
#if __has_builtin(__builtin_amdgcn_mfma_f32_16x16x16bf16_1k)
    return __builtin_amdgcn_mfma_f32_16x16x16bf16_1k(a, b, c, 0, 0, 0);
#elif __has_builtin(__builtin_amdgcn_mfma_f32_16x16x16_bf16)
    return __builtin_amdgcn_mfma_f32_16x16x16_bf16(a, b, c, 0, 0, 0);
#else
    f32x4 d;
    asm volatile("v_mfma_f32_16x16x16_bf16 %0, %1, %2, %3"
                 : "=v"(d) : "v"(a), "v"(b), "v"(c));
    return d;
#endif
}

// ---------------- Kernel 0: weight convert + transpose to bf16 ----------------
__global__ __launch_bounds__(256) void wconv(const float* __restrict__ Wq,
                                             const float* __restrict__ Wk,
                                             const float* __restrict__ Wv,
                                             const float* __restrict__ Wo,
                                             u16* wq_t, u16* wk_t, u16* wv_t, u16* wo_t) {
    int id = blockIdx.x * 256 + threadIdx.x;
    if (id < 3 * 65536) {
        int m = id / 65536;
        int e = id % 65536;
        int k = e >> 9, n = e & 511;
        const float* W = (m == 0) ? Wq : ((m == 1) ? Wk : Wv);
        u16* Wt = (m == 0) ? wq_t : ((m == 1) ? wk_t : wv_t);
        Wt[n * 128 + k] = f32_to_bf16(W[e]);
    } else {
        int e = id - 3 * 65536;
        int k = e >> 7, n = e & 127;
        wo_t[n * 512 + k] = f32_to_bf16(Wo[e]);
    }
}

// ---------------- Kernel 1: QKV projection GEMM ----------------
// q stored PRE-SCALED by (1/sqrt(32))*log2(e).
__global__ __launch_bounds__(256) void qkv_proj(const float* __restrict__ pair,
                                                const u16* __restrict__ wq_t,
                                                const u16* __restrict__ wk_t,
                                                const u16* __restrict__ wv_t,
                                                const float* __restrict__ bq,
                                                const float* __restrict__ bk,
                                                const float* __restrict__ bv,
                                                u16* __restrict__ q_ws,
                                                u16* __restrict__ k_ws,
                                                u16* __restrict__ vT_ws) {
    __shared__ u16 As[128 * 136];
    __shared__ u16 Bs[64 * 136];
    const int tid = threadIdx.x;
    const int m0 = blockIdx.x * 128;

    for (int it = 0; it < 16; ++it) {
        int L = tid + it * 256;
        int row = L >> 5, c4 = L & 31;
        const float4 v = *(reinterpret_cast<const float4*>(pair + (size_t)(m0 + row) * 128) + c4);
        ushort4 pk;
        pk.x = f32_to_bf16(v.x); pk.y = f32_to_bf16(v.y);
        pk.z = f32_to_bf16(v.z); pk.w = f32_to_bf16(v.w);
        *reinterpret_cast<ushort4*>(&As[row * 136 + c4 * 4]) = pk;
    }

    const int wave = tid >> 6, lane = tid & 63;
    const int g = lane >> 4, l15 = lane & 15;

    for (int nt = 0; nt < 24; ++nt) {
        const int mat = nt >> 3;
        const int ncol0 = (nt & 7) * 64;
        const u16* Wt = (mat == 0) ? wq_t : ((mat == 1) ? wk_t : wv_t);
        const float* bias = (mat == 0) ? bq : ((mat == 1) ? bk : bv);

        __syncthreads();
        for (int it = 0; it < 4; ++it) {
            int L = tid + it * 256;
            int n = L >> 4, seg = L & 15;
            *reinterpret_cast<s16x8*>(&Bs[n * 136 + seg * 8]) =
                *reinterpret_cast<const s16x8*>(Wt + (size_t)(ncol0 + n) * 128 + seg * 8);
        }
        __syncthreads();

        f32x4 acc[2][4];
        for (int r = 0; r < 2; ++r) for (int c = 0; c < 4; ++c) acc[r][c] = f32x4{0.f, 0.f, 0.f, 0.f};

        for (int kk = 0; kk < 4; ++kk) {
            s16x8 a[2], b[4];
            a[0] = *reinterpret_cast<s16x8*>(&As[(wave * 32 + l15) * 136 + kk * 32 + g * 8]);
            a[1] = *reinterpret_cast<s16x8*>(&As[(wave * 32 + 16 + l15) * 136 + kk * 32 + g * 8]);
            for (int c = 0; c < 4; ++c)
                b[c] = *reinterpret_cast<s16x8*>(&Bs[(c * 16 + l15) * 136 + kk * 32 + g * 8]);
            for (int r = 0; r < 2; ++r)
                for (int c = 0; c < 4; ++c)
                    acc[r][c] = __builtin_amdgcn_mfma_f32_16x16x32_bf16(a[r], b[c], acc[r][c], 0, 0, 0);
        }

        const float sc = (mat == 0) ? (QSCALE) : 1.0f;
        for (int r = 0; r < 2; ++r) {
            for (int c = 0; c < 4; ++c) {
                const int col = ncol0 + c * 16 + l15;
                const float bval = bias[col];
                const int rowb = m0 + wave * 32 + r * 16 + g * 4;
                if (mat < 2) {
                    u16* dst = (mat == 0) ? q_ws : k_ws;
                    for (int rr = 0; rr < 4; ++rr)
                        dst[(size_t)(rowb + rr) * 512 + col] = f32_to_bf16((acc[r][c][rr] + bval) * sc);
                } else {
                    const int i_ = rowb >> 8, j_ = rowb & 255;
                    u16* dst = vT_ws + ((size_t)i_ * 512 + col) * 256 + j_;
                    for (int p = 0; p < 2; ++p) {
                        unsigned int pack = (unsigned)f32_to_bf16(acc[r][c][2 * p] + bval) |
                                            ((unsigned)f32_to_bf16(acc[r][c][2 * p + 1] + bval) << 16);
                        *reinterpret_cast<unsigned int*>(dst + 2 * p) = pack;
                    }
                }
            }
        }
    }
}

// ---------------- Kernel 2: triangular attention per (i,h) ----------------
// Swapped QK^T: lane(g,l15) holds S[j=l15][k=kt*16+g*4+r] -> P stays in registers
// and feeds mfma_16x16x16 B-fragments directly. Triangle-skipped (kt <= t).
// o overwrites q in-place (each row's Q read and O write are in the same wave).
__global__ __launch_bounds__(256, 4) void attn(const u16* __restrict__ k_ws,
                                               const u16* __restrict__ vT_ws,
                                               u16* qo_ws) {
    __shared__ u16 Ks[256 * 40];    // 256 k-rows x 32 c, pitch 40
    __shared__ u16 Vt[32 * 264];    // 32 c x 256 keys, pitch 264

    // XCD-chunked swizzle: all 16 h-blocks of an i land on one XCD (4096 = 8*512).
    const int bx = ((blockIdx.x & 7) << 9) | (blockIdx.x >> 3);
    const int i = bx >> 4, h = bx & 15;
    const int tid = threadIdx.x;
    const size_t base = ((size_t)i * 256) * 512 + h * 32;

    for (int it = 0; it < 4; ++it) {
        int L = tid + it * 256;
        int row = L >> 2, seg = L & 3;
        *reinterpret_cast<s16x8*>(&Ks[row * 40 + seg * 8]) =
            *reinterpret_cast<const s16x8*>(k_ws + base + (size_t)row * 512 + seg * 8);
    }
    const size_t vbase = ((size_t)i * 512 + h * 32) * 256;
    for (int it = 0; it < 4; ++it) {
        int L = tid + it * 256;
        int c = L >> 5, seg = L & 31;
        *reinterpret_cast<s16x8*>(&Vt[c * 264 + seg * 8]) =
            *reinterpret_cast<const s16x8*>(vT_ws + vbase + (size_t)c * 256 + seg * 8);
    }
    __syncthreads();

    const int wave = tid >> 6, lane = tid & 63;
    const int g = lane >> 4, l15 = lane & 15;

    for (int ch = 0; ch < 4; ++ch) {
        // balanced chunk assignment: each wave's ktmax sums to 34
        const int t = (ch == 0) ? wave : (ch == 1) ? (7 - wave) : (ch == 2) ? (8 + wave) : (15 - wave);
        const int jbase = t * 16;
        const int ktmax = t + 1;

        // Q fragment (B operand of swapped QK^T): row j=jbase+l15, cols g*8..+8
        const s16x8 qf = *reinterpret_cast<const s16x8*>(
            qo_ws + base + (size_t)(jbase + l15) * 512 + g * 8);

        f32x4 o0 = {0.f, 0.f, 0.f, 0.f}, o1 = {0.f, 0.f, 0.f, 0.f};
        float sum = 0.f;

        for (int kt = 0; kt < ktmax; ++kt) {
            const s16x8 kf = *reinterpret_cast<s16x8*>(&Ks[(kt * 16 + l15) * 40 + g * 8]);
            f32x4 s = __builtin_amdgcn_mfma_f32_16x16x32_bf16(kf, qf, f32x4{0.f, 0.f, 0.f, 0.f}, 0, 0, 0);
            // s[r] = S[j=jbase+l15][k = kt*16 + g*4 + r] (pre-scaled, log2 domain)
            float p0, p1, p2, p3;
            if (kt == t) {  // diagonal tile: mask k > j
                p0 = ((g * 4 + 0) > l15) ? 0.f : fast_exp2(s[0]);
                p1 = ((g * 4 + 1) > l15) ? 0.f : fast_exp2(s[1]);
                p2 = ((g * 4 + 2) > l15) ? 0.f : fast_exp2(s[2]);
                p3 = ((g * 4 + 3) > l15) ? 0.f : fast_exp2(s[3]);
            } else {
                p0 = fast_exp2(s[0]); p1 = fast_exp2(s[1]);
                p2 = fast_exp2(s[2]); p3 = fast_exp2(s[3]);
            }
            sum += (p0 + p1) + (p2 + p3);
            // pack to 4 bf16 (round-half-up) = B-fragment of mfma_16x16x16
            unsigned e0 = __builtin_bit_cast(unsigned, p0) + 0x8000u;
            unsigned e1 = __builtin_bit_cast(unsigned, p1) + 0x8000u;
            unsigned e2 = __builtin_bit_cast(unsigned, p2) + 0x8000u;
            unsigned e3 = __builtin_bit_cast(unsigned, p3) + 0x8000u;
            uint2 pw;
            pw.x = __builtin_amdgcn_perm(e1, e0, 0x07060302u);
            pw.y = __builtin_amdgcn_perm(e3, e2, 0x07060302u);
            const s16x4 pb = __builtin_bit_cast(s16x4, pw);
            // V^T A-fragments: row c (=l15 / 16+l15), k = kt*16 + g*4 .. +4
            const s16x4 va0 = *reinterpret_cast<s16x4*>(&Vt[l15 * 264 + kt * 16 + g * 4]);
            const s16x4 va1 = *reinterpret_cast<s16x4*>(&Vt[(16 + l15) * 264 + kt * 16 + g * 4]);
            o0 = mfma_16x16x16_bf16(va0, pb, o0);
            o1 = mfma_16x16x16_bf16(va1, pb, o1);
        }

        // row sum lives split across the 4 g-lanes of the same j=l15
        sum += __shfl_xor(sum, 16, 64);
        sum += __shfl_xor(sum, 32, 64);
        const float rinv = 1.0f / sum;

        // o0[r] = O[j=l15][c=g*4+r], o1 -> c+16 ; store 8B packed
        unsigned x0 = __builtin_bit_cast(unsigned, o0[0] * rinv) + 0x8000u;
        unsigned x1 = __builtin_bit_cast(unsigned, o0[1] * rinv) + 0x8000u;
        unsigned x2 = __builtin_bit_cast(unsigned, o0[2] * rinv) + 0x8000u;
        unsigned x3 = __builtin_bit_cast(unsigned, o0[3] * rinv) + 0x8000u;
        uint2 w0;
        w0.x = __builtin_amdgcn_perm(x1, x0, 0x07060302u);
        w0.y = __builtin_amdgcn_perm(x3, x2, 0x07060302u);
        unsigned y0 = __builtin_bit_cast(unsigned, o1[0] * rinv) + 0x8000u;
        unsigned y1 = __builtin_bit_cast(unsigned, o1[1] * rinv) + 0x8000u;
        unsigned y2 = __builtin_bit_cast(unsigned, o1[2] * rinv) + 0x8000u;
        unsigned y3 = __builtin_bit_cast(unsigned, o1[3] * rinv) + 0x8000u;
        uint2 w1;
        w1.x = __builtin_amdgcn_perm(y1, y0, 0x07060302u);
        w1.y = __builtin_amdgcn_perm(y3, y2, 0x07060302u);

        u16* orow = qo_ws + base + (size_t)(jbase + l15) * 512;
        *reinterpret_cast<uint2*>(orow + g * 4) = w0;
        *reinterpret_cast<uint2*>(orow + 16 + g * 4) = w1;
    }
}

// ---------------- Kernel 3: output projection + residual ----------------
__global__ __launch_bounds__(256) void outproj(const u16* __restrict__ o_ws,
                                               const u16* __restrict__ wo_t,
                                               const float* __restrict__ pair,
                                               const float* __restrict__ bo,
                                               float* __restrict__ out) {
    __shared__ u16 As[64 * 72];
    __shared__ u16 Bs[128 * 72];
    const int tid = threadIdx.x;
    const int m0 = blockIdx.x * 64;
    const int wave = tid >> 6, lane = tid & 63;
    const int g = lane >> 4, l15 = lane & 15;

    f32x4 acc[8];
    for (int c = 0; c < 8; ++c) acc[c] = f32x4{0.f, 0.f, 0.f, 0.f};

    for (int kt = 0; kt < 8; ++kt) {
        __syncthreads();
        for (int it = 0; it < 2; ++it) {
            int L = tid + it * 256;
            int row = L >> 3, seg = L & 7;
            *reinterpret_cast<s16x8*>(&As[row * 72 + seg * 8]) =
                *reinterpret_cast<const s16x8*>(o_ws + (size_t)(m0 + row) * 512 + kt * 64 + seg * 8);
        }
        for (int it = 0; it < 4; ++it) {
            int L = tid + it * 256;
            int n = L >> 3, seg = L & 7;
            *reinterpret_cast<s16x8*>(&Bs[n * 72 + seg * 8]) =
                *reinterpret_cast<const s16x8*>(wo_t + (size_t)n * 512 + kt * 64 + seg * 8);
        }
        __syncthreads();
        for (int kk = 0; kk < 2; ++kk) {
            const s16x8 a = *reinterpret_cast<s16x8*>(&As[(wave * 16 + l15) * 72 + kk * 32 + g * 8]);
            for (int c = 0; c < 8; ++c) {
                const s16x8 b = *reinterpret_cast<s16x8*>(&Bs[(c * 16 + l15) * 72 + kk * 32 + g * 8]);
                acc[c] = __builtin_amdgcn_mfma_f32_16x16x32_bf16(a, b, acc[c], 0, 0, 0);
            }
        }
    }

    for (int c = 0; c < 8; ++c) {
        const int n = c * 16 + l15;
        const float bias = bo[n];
        for (int r = 0; r < 4; ++r) {
            const size_t row = m0 + wave * 16 + g * 4 + r;
            out[row * 128 + n] = acc[c][r] + bias + pair[row * 128 + n];
        }
    }
}

extern "C" void kernel_launch(void* const* d_in, const int* in_sizes, int n_in,
                              void* d_out, int out_size, void* d_ws, size_t ws_size,
                              hipStream_t stream) {
    const float* pair = (const float*)d_in[0];
    const float* Wq = (const float*)d_in[1];
    const float* bq = (const float*)d_in[2];
    const float* Wk = (const float*)d_in[3];
    const float* bk = (const float*)d_in[4];
    const float* Wv = (const float*)d_in[5];
    const float* bv = (const float*)d_in[6];
    const float* Wo = (const float*)d_in[7];
    const float* bo = (const float*)d_in[8];
    float* out = (float*)d_out;

    char* ws = (char*)d_ws;
    u16* q_ws  = (u16*)(ws);                       // 64 MiB (q, later aliased as o)
    u16* k_ws  = (u16*)(ws + 67108864);            // 64 MiB
    u16* vT_ws = (u16*)(ws + 134217728);           // 64 MiB
    u16* wq_t  = (u16*)(ws + 201326592);
    u16* wk_t  = wq_t + 65536;
    u16* wv_t  = wk_t + 65536;
    u16* wo_t  = wv_t + 65536;

    wconv<<<1024, 256, 0, stream>>>(Wq, Wk, Wv, Wo, wq_t, wk_t, wv_t, wo_t);
    qkv_proj<<<512, 256, 0, stream>>>(pair, wq_t, wk_t, wv_t, bq, bk, bv, q_ws, k_ws, vT_ws);
    attn<<<4096, 256, 0, stream>>>(k_ws, vT_ws, q_ws);
    outproj<<<1024, 256, 0, stream>>>(q_ws, wo_t, pair, bo, out);
}